// Round 12
// baseline (140.134 us; speedup 1.0000x reference)
//
#include <hip/hip_runtime.h>
#include <hip/hip_bf16.h>
#include <math.h>

#define NNODE 3000
#define NCHUNK 47  // ceil(3000/64)
#define NBPR 376   // bytes per bitmask row (47*8)
#define ALPHA 0.2f
#define LDT 3008   // ushorts per WhT plane-row group (47 tiles * 64)
#define LOG2E 1.4426950408889634f

typedef __attribute__((ext_vector_type(8))) short short8v;
typedef __attribute__((ext_vector_type(4))) short short4v;
typedef __attribute__((ext_vector_type(4))) float float4v;

static __device__ __forceinline__ short f2b(float x) {
  __hip_bfloat16 b = __float2bfloat16(x);
  return *reinterpret_cast<short*>(&b);
}
static __device__ __forceinline__ float b2f(unsigned short u) {
  unsigned v = ((unsigned)u) << 16;
  return *reinterpret_cast<float*>(&v);
}

// ---------------- fused preprocessing: one launch, concurrent regions ----------------
#define PB_BM 8813
#define PB_XC 750
#define PB_W1 64
#define PB_WI 8
#define PB_WF 4
#define PB_W2 8
#define PREP_BLOCKS (PB_BM + PB_XC + PB_W1 + PB_WI + PB_WF + PB_W2)

static __device__ __forceinline__ void cast8(const float* __restrict__ src,
                                             unsigned short* __restrict__ dst, int i) {
  float4 va = reinterpret_cast<const float4*>(src)[2 * i];
  float4 vb = reinterpret_cast<const float4*>(src)[2 * i + 1];
  short8v w;
  w[0] = f2b(va.x); w[1] = f2b(va.y); w[2] = f2b(va.z); w[3] = f2b(va.w);
  w[4] = f2b(vb.x); w[5] = f2b(vb.y); w[6] = f2b(vb.z); w[7] = f2b(vb.w);
  reinterpret_cast<short8v*>(dst)[i] = w;
}

static __device__ void wt_body(const float* __restrict__ src,
                               unsigned short* __restrict__ dst,
                               int rows, int O, int ldT, int m0, float* Lw) {
  const int tid = threadIdx.x;
  const int ocnt = O / 4;
  for (int idx = tid; idx < 64 * ocnt; idx += 256) {
    int m = idx / ocnt, oc = idx % ocnt;
    float4 v = make_float4(0.f, 0.f, 0.f, 0.f);
    if (m0 + m < rows)
      v = *reinterpret_cast<const float4*>(&src[(size_t)(m0 + m) * O + 4 * oc]);
    *reinterpret_cast<float4*>(&Lw[m * 68 + 4 * oc]) = v;
  }
  __syncthreads();
  const int o = tid & (O - 1);
  for (int mc = tid / O; mc < 8; mc += 256 / O) {
    short8v w;
#pragma unroll
    for (int j = 0; j < 8; ++j) w[j] = f2b(Lw[(8 * mc + j) * 68 + o]);
    *reinterpret_cast<short8v*>(&dst[(size_t)o * ldT + m0 + 8 * mc]) = w;
  }
}

__global__ __launch_bounds__(256)
void k_prep(const int* __restrict__ adj, unsigned char* __restrict__ bmb,
            const float* __restrict__ x, unsigned short* __restrict__ xb,
            const float* __restrict__ W1, unsigned short* __restrict__ W1Tb,
            const float* __restrict__ wint1, unsigned short* __restrict__ wint1b,
            const float* __restrict__ wfus1, unsigned short* __restrict__ wfus1b,
            const float* __restrict__ W2, unsigned short* __restrict__ W2Tb) {
  __shared__ float Lw[64 * 68];
  const int b = blockIdx.x;
  const int tid = threadIdx.x;
  if (b < PB_BM) {
    int idx = b * 256 + tid;
    if (idx < 2 * NNODE * NBPR) {
      int row = idx / NBPR, by = idx % NBPR;
      unsigned char v = 0;
      if (by < 375) {
        const int* p = adj + (size_t)row * NNODE + 8 * by;
        int4 a0 = *reinterpret_cast<const int4*>(p);
        int4 a1 = *reinterpret_cast<const int4*>(p + 4);
        v = (unsigned char)((a0.x > 0) | ((a0.y > 0) << 1) | ((a0.z > 0) << 2) |
                            ((a0.w > 0) << 3) | ((a1.x > 0) << 4) | ((a1.y > 0) << 5) |
                            ((a1.z > 0) << 6) | ((a1.w > 0) << 7));
      }
      bmb[idx] = v;
    }
  } else if (b < PB_BM + PB_XC) {
    int i = (b - PB_BM) * 256 + tid;
    if (i < 192000) cast8(x, xb, i);
  } else if (b < PB_BM + PB_XC + PB_W1) {
    int zb = b - (PB_BM + PB_XC);
    int z = zb >> 3, m0 = (zb & 7) * 64;
    wt_body(W1 + (size_t)z * 512 * 64, W1Tb + (size_t)z * 64 * 512, 512, 64, 512, m0, Lw);
  } else if (b < PB_BM + PB_XC + PB_W1 + PB_WI) {
    int i = (b - (PB_BM + PB_XC + PB_W1)) * 256 + tid;
    if (i < 2048) cast8(wint1, wint1b, i);
  } else if (b < PB_BM + PB_XC + PB_W1 + PB_WI + PB_WF) {
    int i = (b - (PB_BM + PB_XC + PB_W1 + PB_WI)) * 256 + tid;
    if (i < 1024) cast8(wfus1, wfus1b, i);
  } else {
    int z = b - (PB_BM + PB_XC + PB_W1 + PB_WI + PB_WF);
    wt_body(W2 + (size_t)z * 64 * 32, W2Tb + (size_t)z * 32 * 64, 64, 32, 64, 0, Lw);
  }
}

// ---------------- bf16 MFMA GEMM, 32 rows x OW cols per 128-thr block ----------------
// AF=1: A-tile generated from stage-1 PV partials (normalize+ELU+bf16 on the fly).
// MODE=1: epilogue writes WhT in PRE-SWIZZLED tile layout: tile t = rows [64t,64t+64),
//   byte offset within tile = (o*128 + (m&63)*2) ^ ((o&7)<<4); tile stride = OW*128 B.
template <int OW, int KC, int MODE, int ACT, int AF>
__global__ __launch_bounds__(128)
void k_xw(const unsigned short* __restrict__ Ab, long long boffA,
          const unsigned short* __restrict__ Bb, long long boffB,
          const float* __restrict__ aux,
          unsigned short* __restrict__ Wo,
          long long boffW,
          float* __restrict__ f1o, float* __restrict__ f2o,
          const float* __restrict__ rs4,
          int colStrideZ, int ldC) {
  constexpr int NCT = OW / 16;
  const int z = blockIdx.z;
  const int n0 = blockIdx.x * 32;
  const int ocol0 = blockIdx.y * OW;
  const unsigned short* A = Ab + (AF ? 0 : boffA * z);
  const unsigned short* B = Bb + boffB * z;
  const int tid = threadIdx.x;
  const int l = tid & 63, g = l >> 4, li = l & 15;
  const int r0 = 16 * (tid >> 6);
  __shared__ __align__(16) unsigned short As[32 * 64];
  __shared__ __align__(16) unsigned short Bs[OW * 64];
  float4v acc[NCT];
#pragma unroll
  for (int ct = 0; ct < NCT; ++ct) acc[ct] = {0.f, 0.f, 0.f, 0.f};
  for (int k0 = 0; k0 < KC; k0 += 64) {
    for (int i = tid; i < 256; i += 128) {
      int r = i >> 3, c8 = i & 7;
      uint4 v = {0u, 0u, 0u, 0u};
      int n = n0 + r;
      if (n < NNODE) {
        if (AF) {
          // stage-1 PV partials: h = k0/64, zp = a*4+h; val = ELU((Σks p)·inv)
          int zp = z * 4 + (k0 >> 6);
          float s = rs4[(size_t)(0 * 8 + zp) * NNODE + n] +
                    rs4[(size_t)(1 * 8 + zp) * NNODE + n] +
                    rs4[(size_t)(2 * 8 + zp) * NNODE + n] +
                    rs4[(size_t)(3 * 8 + zp) * NNODE + n];
          float inv = (s > 0.f) ? 1.f / s : 0.f;
          size_t base = ((size_t)zp * NNODE + n) * 64 + 8 * c8;
          short8v p0 = *reinterpret_cast<const short8v*>(A + base);
          short8v p1 = *reinterpret_cast<const short8v*>(A + (size_t)8 * NNODE * 64 + base);
          short8v p2 = *reinterpret_cast<const short8v*>(A + (size_t)16 * NNODE * 64 + base);
          short8v p3 = *reinterpret_cast<const short8v*>(A + (size_t)24 * NNODE * 64 + base);
          short8v w;
#pragma unroll
          for (int e = 0; e < 8; ++e) {
            float sv = b2f((unsigned short)p0[e]) + b2f((unsigned short)p1[e]) +
                       b2f((unsigned short)p2[e]) + b2f((unsigned short)p3[e]);
            sv *= inv;
            sv = sv > 0.f ? sv : (__expf(sv) - 1.f);
            w[e] = f2b(sv);
          }
          v = *reinterpret_cast<uint4*>(&w);
        } else {
          v = *reinterpret_cast<const uint4*>(A + (size_t)n * KC + k0 + 8 * c8);
        }
      }
      int boff = (r * 128 + c8 * 16) ^ ((r & 7) << 4);
      *reinterpret_cast<uint4*>(reinterpret_cast<char*>(As) + boff) = v;
    }
    for (int i = tid; i < OW * 8; i += 128) {
      int ro = i >> 3, c8 = i & 7;
      uint4 v = *reinterpret_cast<const uint4*>(B + (size_t)(ocol0 + ro) * KC + k0 + 8 * c8);
      int boff = (ro * 128 + c8 * 16) ^ ((ro & 7) << 4);
      *reinterpret_cast<uint4*>(reinterpret_cast<char*>(Bs) + boff) = v;
    }
    __syncthreads();
#pragma unroll
    for (int q = 0; q < 2; ++q) {
      int aoff = ((r0 + li) * 128 + q * 64 + 16 * g) ^ ((li & 7) << 4);
      short8v afr = *reinterpret_cast<const short8v*>(
          reinterpret_cast<const char*>(As) + aoff);
#pragma unroll
      for (int ct = 0; ct < NCT; ++ct) {
        int orow = ct * 16 + li;
        int boff = (orow * 128 + q * 64 + 16 * g) ^ ((li & 7) << 4);
        short8v bfr = *reinterpret_cast<const short8v*>(
            reinterpret_cast<const char*>(Bs) + boff);
        acc[ct] = __builtin_amdgcn_mfma_f32_16x16x32_bf16(afr, bfr, acc[ct], 0, 0, 0);
      }
    }
    __syncthreads();
  }
  if (MODE == 1) {
    const float* av = aux + (size_t)z * 2 * OW;
    float p1[4] = {0.f, 0.f, 0.f, 0.f}, p2[4] = {0.f, 0.f, 0.f, 0.f};
#pragma unroll
    for (int ct = 0; ct < NCT; ++ct) {
      float a1v = av[ct * 16 + li];
      float a2v = av[OW + ct * 16 + li];
#pragma unroll
      for (int j = 0; j < 4; ++j) {
        p1[j] += acc[ct][j] * a1v;
        p2[j] += acc[ct][j] * a2v;
      }
    }
#pragma unroll
    for (int off = 1; off < 16; off <<= 1) {
#pragma unroll
      for (int j = 0; j < 4; ++j) {
        p1[j] += __shfl_xor(p1[j], off);
        p2[j] += __shfl_xor(p2[j], off);
      }
    }
    // pre-swizzled tile write (matches pvp's LDS image exactly)
    unsigned short* WT = Wo + boffW * z;
    const int m = n0 + r0 + 4 * g;
    const int tile = m >> 6, mloc = m & 63;
    char* tbase = reinterpret_cast<char*>(WT) + (size_t)tile * (OW * 128);
#pragma unroll
    for (int ct = 0; ct < NCT; ++ct) {
      int o = ocol0 + ct * 16 + li;
      short4v w;
#pragma unroll
      for (int j = 0; j < 4; ++j) w[j] = f2b(acc[ct][j]);
      int boff = (o * 128 + mloc * 2) ^ ((o & 7) << 4);
      *reinterpret_cast<short4v*>(tbase + boff) = w;
    }
    if (li == 0) {
#pragma unroll
      for (int j = 0; j < 4; ++j) {
        int n = n0 + r0 + 4 * g + j;
        if (n < NNODE) {
          f1o[(size_t)z * NNODE + n] = p1[j] * LOG2E;
          f2o[(size_t)z * NNODE + n] = p2[j] * LOG2E;
        }
      }
    }
  } else {
#pragma unroll
    for (int ct = 0; ct < NCT; ++ct) {
      float b = aux[ocol0 + ct * 16 + li];
#pragma unroll
      for (int j = 0; j < 4; ++j) {
        int n = n0 + r0 + 4 * g + j;
        if (n < NNODE) {
          float v = acc[ct][j] + b;
          if (ACT == 1) v = v > 0.f ? v : (__expf(v) - 1.f);
          Wo[(size_t)n * ldC + z * colStrideZ + ocol0 + ct * 16 + li] = (unsigned short)f2b(v);
        }
      }
    }
  }
}

// ---------------- MFMA PV, K-split partials: 64 rows, 256 thr, 4 waves ----------------
// WhT is pre-swizzled per 64-k tile -> staging is a LINEAR 16B copy.
template <int O, int CPS, bool PB16>
__global__ __launch_bounds__(256)
void k_pvp(const unsigned short* __restrict__ WhT,
           const float* __restrict__ f1, const float* __restrict__ f2,
           const unsigned long long* __restrict__ bm,
           void* __restrict__ Cpart, float* __restrict__ rsum) {
  constexpr int NCT = O / 16;
  const int z = blockIdx.z, a = z >> 2;
  const int ks = blockIdx.y;
  const int n0 = blockIdx.x * 64;
  const int kc0 = ks * CPS;
  const int nch = (NCHUNK - kc0 < CPS) ? (NCHUNK - kc0) : CPS;
  const int tid = threadIdx.x;
  const int l = tid & 63, li = l & 15, g = l >> 4;
  const int r0 = 16 * (tid >> 6);  // 0,16,32,48 (4 waves)
  const unsigned short* WT = WhT + (size_t)z * O * LDT;
  const float* f2B = f2 + (size_t)z * NNODE;
  const unsigned long long* bmA = bm + (size_t)a * NNODE * NCHUNK;
  __shared__ __align__(16) unsigned short Whs[2][O * 64];
  __shared__ __align__(16) float F2d[2][64];
  __shared__ unsigned long long Bw2[2][64];
  __shared__ float F1s[64];
  if (tid < 64) {
    int n = n0 + tid;
    F1s[tid] = (n < NNODE) ? f1[(size_t)z * NNODE + n] : 0.f;
  }
  short8v onesf;
  {
    short ov = (li == 0) ? (short)0x3F80 : (short)0;
#pragma unroll
    for (int e = 0; e < 8; ++e) onesf[e] = ov;
  }
  auto stage = [&](int t, int buf) {
    if (tid < 64) {
      int n = n0 + tid;
      Bw2[buf][tid] = (n < NNODE) ? bmA[(size_t)n * NCHUNK + kc0 + t] : 0ULL;
    } else if (tid < 128) {
      int m = (kc0 + t) * 64 + (tid - 64);
      F2d[buf][tid - 64] = (m < NNODE) ? f2B[m] : 0.f;
    }
    const uint4* tb = reinterpret_cast<const uint4*>(WT + (size_t)(kc0 + t) * (O * 64));
    uint4* lb = reinterpret_cast<uint4*>(Whs[buf]);
#pragma unroll
    for (int i = tid; i < O * 8; i += 256) lb[i] = tb[i];
  };
  float4v acc[NCT];
#pragma unroll
  for (int ct = 0; ct < NCT; ++ct) acc[ct] = {0.f, 0.f, 0.f, 0.f};
  float4v accs = {0.f, 0.f, 0.f, 0.f};
  stage(0, 0);
  __syncthreads();
  for (int t = 0; t < nch; ++t) {
    int buf = t & 1;
    if (t + 1 < nch) stage(t + 1, buf ^ 1);
    const unsigned long long bwr = Bw2[buf][r0 + li];
    const float f1v = F1s[r0 + li];
    short8v afr[2];
#pragma unroll
    for (int q = 0; q < 2; ++q) {
      int koff = 32 * q + 8 * g;
      unsigned bits = (unsigned)(bwr >> koff) & 0xffu;
      const float4 fa = *reinterpret_cast<const float4*>(&F2d[buf][koff]);
      const float4 fb = *reinterpret_cast<const float4*>(&F2d[buf][koff + 4]);
      float f2v[8] = {fa.x, fa.y, fa.z, fa.w, fb.x, fb.y, fb.z, fb.w};
#pragma unroll
      for (int e = 0; e < 8; ++e) {
        float tt = f1v + f2v[e];
        tt = fmaxf(tt, ALPHA * tt);
        tt = (bits & (1u << e)) ? tt : -1.0e30f;   // exp2(-1e30) = 0
        afr[q][e] = f2b(__builtin_amdgcn_exp2f(tt));
      }
    }
#pragma unroll
    for (int ct = 0; ct < NCT; ++ct) {
      int orow = ct * 16 + li;
#pragma unroll
      for (int q = 0; q < 2; ++q) {
        int boff = (orow * 128 + q * 64 + 16 * g) ^ ((li & 7) << 4);
        short8v bfr = *reinterpret_cast<const short8v*>(
            reinterpret_cast<const char*>(Whs[buf]) + boff);
        acc[ct] = __builtin_amdgcn_mfma_f32_16x16x32_bf16(afr[q], bfr, acc[ct], 0, 0, 0);
      }
    }
    accs = __builtin_amdgcn_mfma_f32_16x16x32_bf16(afr[0], onesf, accs, 0, 0, 0);
    accs = __builtin_amdgcn_mfma_f32_16x16x32_bf16(afr[1], onesf, accs, 0, 0, 0);
    __syncthreads();
  }
  if (PB16) {
    unsigned short* Cp = (unsigned short*)Cpart + ((size_t)ks * 8 + z) * NNODE * O;
#pragma unroll
    for (int j = 0; j < 4; ++j) {
      int n = n0 + r0 + 4 * g + j;
      if (n < NNODE) {
#pragma unroll
        for (int ct = 0; ct < NCT; ++ct)
          Cp[(size_t)n * O + ct * 16 + li] = (unsigned short)f2b(acc[ct][j]);
      }
    }
  } else {
    float* Cp = (float*)Cpart + ((size_t)ks * 8 + z) * NNODE * O;
#pragma unroll
    for (int j = 0; j < 4; ++j) {
      int n = n0 + r0 + 4 * g + j;
      if (n < NNODE) {
#pragma unroll
        for (int ct = 0; ct < NCT; ++ct)
          Cp[(size_t)n * O + ct * 16 + li] = acc[ct][j];
      }
    }
  }
  if (li == 0) {
#pragma unroll
    for (int j = 0; j < 4; ++j) {
      int n = n0 + r0 + 4 * g + j;
      if (n < NNODE) rsum[((size_t)ks * 8 + z) * NNODE + n] = accs[j];
    }
  }
}

// ---------------- fused tail: pvred2 + int2 + fus2 + log_softmax (+ L1) ----------
__global__ __launch_bounds__(256)
void k_tail(const float* __restrict__ Cpf, const float* __restrict__ rs4,
            const float* __restrict__ wint2, const float* __restrict__ bint2,
            const float* __restrict__ wfus2, const float* __restrict__ bfus2,
            const float* __restrict__ wfus1, float* __restrict__ out) {
  const int tid = threadIdx.x;
  if (blockIdx.x == 750) {
    __shared__ float red[256];
    float s1 = 0.f, s2 = 0.f;
    for (int i = tid; i < 64 * 128; i += 256) s1 += fabsf(wfus1[i]);
    if (tid < 128) s2 = fabsf(wfus2[tid]);
    red[tid] = s1 / 8192.f + s2 / 128.f;
    __syncthreads();
    for (int off = 128; off; off >>= 1) {
      if (tid < off) red[tid] += red[tid + off];
      __syncthreads();
    }
    if (tid == 0) out[24000] = red[0];
    return;
  }
  __shared__ float T2s[4][16];
  const int w = tid >> 6, l = tid & 63;
  const int n = blockIdx.x * 4 + w;
  const int o = l & 15, q = l >> 4;     // t2 output index, k-quarter (== head h)
  const int zz = o >> 3, c = o & 7;
  const int zp = zz * 4 + q;
  float s4 = rs4[(size_t)(0 * 8 + zp) * NNODE + n] +
             rs4[(size_t)(1 * 8 + zp) * NNODE + n] +
             rs4[(size_t)(2 * 8 + zp) * NNODE + n] +
             rs4[(size_t)(3 * 8 + zp) * NNODE + n];
  float inv = (s4 > 0.f) ? 1.f / s4 : 0.f;
  const float* wr = wint2 + (size_t)c * 128 + q * 32;
  size_t base = ((size_t)zp * NNODE + n) * 32;
  const size_t pls = (size_t)8 * NNODE * 32;  // ks-plane stride
  float s = 0.f;
#pragma unroll
  for (int i = 0; i < 8; ++i) {
    float4 p0 = *reinterpret_cast<const float4*>(Cpf + base + 4 * i);
    float4 p1 = *reinterpret_cast<const float4*>(Cpf + pls + base + 4 * i);
    float4 p2 = *reinterpret_cast<const float4*>(Cpf + 2 * pls + base + 4 * i);
    float4 p3 = *reinterpret_cast<const float4*>(Cpf + 3 * pls + base + 4 * i);
    float4 wv = *reinterpret_cast<const float4*>(wr + 4 * i);
    float v0 = (p0.x + p1.x + p2.x + p3.x) * inv;
    float v1 = (p0.y + p1.y + p2.y + p3.y) * inv;
    float v2 = (p0.z + p1.z + p2.z + p3.z) * inv;
    float v3 = (p0.w + p1.w + p2.w + p3.w) * inv;
    v0 = v0 > 0.f ? v0 : (__expf(v0) - 1.f);
    v1 = v1 > 0.f ? v1 : (__expf(v1) - 1.f);
    v2 = v2 > 0.f ? v2 : (__expf(v2) - 1.f);
    v3 = v3 > 0.f ? v3 : (__expf(v3) - 1.f);
    s = fmaf(v0, wv.x, s); s = fmaf(v1, wv.y, s);
    s = fmaf(v2, wv.z, s); s = fmaf(v3, wv.w, s);
  }
  s += __shfl_xor(s, 16);
  s += __shfl_xor(s, 32);
  if (q == 0) {
    float v = s + bint2[c];
    v = v > 0.f ? v : (__expf(v) - 1.f);
    T2s[w][o] = v;
  }
  if (l < 8) {
    float v = bfus2[l];
#pragma unroll
    for (int k = 0; k < 16; ++k) v = fmaf(T2s[w][k], wfus2[l * 16 + k], v);
    float mx = v;
    mx = fmaxf(mx, __shfl_xor(mx, 1, 8));
    mx = fmaxf(mx, __shfl_xor(mx, 2, 8));
    mx = fmaxf(mx, __shfl_xor(mx, 4, 8));
    float ex = __expf(v - mx);
    float sm = ex;
    sm += __shfl_xor(sm, 1, 8);
    sm += __shfl_xor(sm, 2, 8);
    sm += __shfl_xor(sm, 4, 8);
    float ls = __logf(sm) + mx;
    out[(size_t)n * 8 + l] = v - ls;
  }
}

extern "C" void kernel_launch(void* const* d_in, const int* in_sizes, int n_in,
                              void* d_out, int out_size, void* d_ws, size_t ws_size,
                              hipStream_t stream) {
  const float* x = (const float*)d_in[0];
  const int* adj = (const int*)d_in[1];
  const float* W1 = (const float*)d_in[2];
  const float* a1 = (const float*)d_in[3];
  const float* W2 = (const float*)d_in[4];
  const float* a2 = (const float*)d_in[5];
  const float* wint1 = (const float*)d_in[6];
  const float* bint1 = (const float*)d_in[7];
  const float* wfus1 = (const float*)d_in[8];
  const float* bfus1 = (const float*)d_in[9];
  const float* wint2 = (const float*)d_in[10];
  const float* bint2 = (const float*)d_in[11];
  const float* wfus2 = (const float*)d_in[12];
  const float* bfus2 = (const float*)d_in[13];
  float* out = (float*)d_out;

  // workspace layout (float offsets); peak 5,541,600 floats = 22.2 MB
  float* W = (float*)d_ws;
  unsigned long long* bm = (unsigned long long*)d_ws;          // [2][3000][47] = 0..564000
  unsigned short* xb = (unsigned short*)(W + 564000);          // [3000][512] bf16, dead after xw1
  unsigned short* W1Tb = (unsigned short*)(W + 1332000);       // [8][64][512] bf16
  unsigned short* wint1b = (unsigned short*)(W + 1463072);     // [64][256] bf16
  unsigned short* wfus1b = (unsigned short*)(W + 1471264);     // [64][128] bf16
  unsigned short* W2Tb = (unsigned short*)(W + 1475360);       // [8][32][64] bf16
  float* f1b = W + 1483552;                                    // [8][3000]
  float* f2g = W + 1507552;                                    // [8][3000]
  unsigned short* WhT1 = (unsigned short*)(W + 1531552);       // [8][47 tiles][64][64] bf16 swizzled
  unsigned short* t1b = (unsigned short*)(W + 1531552);        // [3000][128] bf16 (after int1)
  unsigned short* out1b = (unsigned short*)(W + 1723552);      // [3000][64] bf16
  unsigned short* WhT2 = (unsigned short*)(W + 1819552);       // [8][47 tiles][32][64] bf16 swizzled
  float* rsumw = W + 2373600;                                  // [4][8][3000]
  void* Cpart = (void*)(W + 2469600);                          // bf16 [4][8][3000][64] / f32 [4][8][3000][32]

  // fused preprocessing (bitmask + casts + weight transposes), one launch
  k_prep<<<dim3(PREP_BLOCKS), 256, 0, stream>>>(
      adj, (unsigned char*)bm, x, xb, W1, W1Tb, wint1, wint1b, wfus1, wfus1b, W2, W2Tb);

  // stage 1: Wh1 + f1/f2 (pre-scaled) + WhT1 (pre-swizzled), fused
  k_xw<64, 512, 1, 0, 0><<<dim3(94, 1, 8), 128, 0, stream>>>(
      xb, 0, W1Tb, 64 * 512, a1, WhT1, (long long)64 * LDT, f1b, f2g, nullptr, 0, 0);
  // PV stage 1 (K-split 4, bf16 partials)
  k_pvp<64, 12, true><<<dim3(47, 4, 8), 256, 0, stream>>>(WhT1, f1b, f2g, bm, Cpart, rsumw);
  // int1 (fused pvred1 in A-path, full-width) -> t1b bf16
  k_xw<64, 256, 0, 1, 1><<<dim3(94, 1, 2), 128, 0, stream>>>(
      (const unsigned short*)Cpart, 0, wint1b, 0, bint1, t1b, 0, nullptr, nullptr,
      rsumw, 64, 128);
  // fus1 (full-width) -> out1b bf16
  k_xw<64, 128, 0, 0, 0><<<dim3(94, 1, 1), 128, 0, stream>>>(
      t1b, 0, wfus1b, 0, bfus1, out1b, 0, nullptr, nullptr, nullptr, 0, 64);

  // stage 2: Wh2 + f1/f2 (pre-scaled) + WhT2 (pre-swizzled), fused
  k_xw<32, 64, 1, 0, 0><<<dim3(94, 1, 8), 128, 0, stream>>>(
      out1b, 0, W2Tb, 32 * 64, a2, WhT2, (long long)32 * LDT, f1b, f2g, nullptr, 0, 0);
  // PV stage 2 (K-split 4, fp32 partials)
  k_pvp<32, 12, false><<<dim3(47, 4, 8), 256, 0, stream>>>(WhT2, f1b, f2g, bm, Cpart, rsumw);

  // fused tail: pvred2 + int2 + fus2 + log_softmax + L1
  k_tail<<<dim3(751), 256, 0, stream>>>(
      (const float*)Cpart, rsumw, wint2, bint2, wfus2, bfus2, wfus1, out);
}

// Round 13
// 135.043 us; speedup vs baseline: 1.0377x; 1.0377x over previous
//
#include <hip/hip_runtime.h>
#include <hip/hip_bf16.h>
#include <math.h>

#define NNODE 3000
#define NCHUNK 47  // ceil(3000/64)
#define NBPR 376   // bytes per bitmask row (47*8)
#define ALPHA 0.2f
#define LDT 3008   // ushorts per WhT plane-row group (47 tiles * 64)
#define LOG2E 1.4426950408889634f

typedef __attribute__((ext_vector_type(8))) short short8v;
typedef __attribute__((ext_vector_type(4))) short short4v;
typedef __attribute__((ext_vector_type(4))) float float4v;

static __device__ __forceinline__ short f2b(float x) {
  __hip_bfloat16 b = __float2bfloat16(x);
  return *reinterpret_cast<short*>(&b);
}
static __device__ __forceinline__ float b2f(unsigned short u) {
  unsigned v = ((unsigned)u) << 16;
  return *reinterpret_cast<float*>(&v);
}

// ---------------- fused preprocessing: one launch, concurrent regions ----------------
#define PB_BM 8813
#define PB_XC 750
#define PB_W1 64
#define PB_WI 8
#define PB_WF 4
#define PB_W2 8
#define PREP_BLOCKS (PB_BM + PB_XC + PB_W1 + PB_WI + PB_WF + PB_W2)

static __device__ __forceinline__ void cast8(const float* __restrict__ src,
                                             unsigned short* __restrict__ dst, int i) {
  float4 va = reinterpret_cast<const float4*>(src)[2 * i];
  float4 vb = reinterpret_cast<const float4*>(src)[2 * i + 1];
  short8v w;
  w[0] = f2b(va.x); w[1] = f2b(va.y); w[2] = f2b(va.z); w[3] = f2b(va.w);
  w[4] = f2b(vb.x); w[5] = f2b(vb.y); w[6] = f2b(vb.z); w[7] = f2b(vb.w);
  reinterpret_cast<short8v*>(dst)[i] = w;
}

static __device__ void wt_body(const float* __restrict__ src,
                               unsigned short* __restrict__ dst,
                               int rows, int O, int ldT, int m0, float* Lw) {
  const int tid = threadIdx.x;
  const int ocnt = O / 4;
  for (int idx = tid; idx < 64 * ocnt; idx += 256) {
    int m = idx / ocnt, oc = idx % ocnt;
    float4 v = make_float4(0.f, 0.f, 0.f, 0.f);
    if (m0 + m < rows)
      v = *reinterpret_cast<const float4*>(&src[(size_t)(m0 + m) * O + 4 * oc]);
    *reinterpret_cast<float4*>(&Lw[m * 68 + 4 * oc]) = v;
  }
  __syncthreads();
  const int o = tid & (O - 1);
  for (int mc = tid / O; mc < 8; mc += 256 / O) {
    short8v w;
#pragma unroll
    for (int j = 0; j < 8; ++j) w[j] = f2b(Lw[(8 * mc + j) * 68 + o]);
    *reinterpret_cast<short8v*>(&dst[(size_t)o * ldT + m0 + 8 * mc]) = w;
  }
}

__global__ __launch_bounds__(256)
void k_prep(const int* __restrict__ adj, unsigned char* __restrict__ bmb,
            const float* __restrict__ x, unsigned short* __restrict__ xb,
            const float* __restrict__ W1, unsigned short* __restrict__ W1Tb,
            const float* __restrict__ wint1, unsigned short* __restrict__ wint1b,
            const float* __restrict__ wfus1, unsigned short* __restrict__ wfus1b,
            const float* __restrict__ W2, unsigned short* __restrict__ W2Tb) {
  __shared__ float Lw[64 * 68];
  const int b = blockIdx.x;
  const int tid = threadIdx.x;
  if (b < PB_BM) {
    int idx = b * 256 + tid;
    if (idx < 2 * NNODE * NBPR) {
      int row = idx / NBPR, by = idx % NBPR;
      unsigned char v = 0;
      if (by < 375) {
        const int* p = adj + (size_t)row * NNODE + 8 * by;
        int4 a0 = *reinterpret_cast<const int4*>(p);
        int4 a1 = *reinterpret_cast<const int4*>(p + 4);
        v = (unsigned char)((a0.x > 0) | ((a0.y > 0) << 1) | ((a0.z > 0) << 2) |
                            ((a0.w > 0) << 3) | ((a1.x > 0) << 4) | ((a1.y > 0) << 5) |
                            ((a1.z > 0) << 6) | ((a1.w > 0) << 7));
      }
      bmb[idx] = v;
    }
  } else if (b < PB_BM + PB_XC) {
    int i = (b - PB_BM) * 256 + tid;
    if (i < 192000) cast8(x, xb, i);
  } else if (b < PB_BM + PB_XC + PB_W1) {
    int zb = b - (PB_BM + PB_XC);
    int z = zb >> 3, m0 = (zb & 7) * 64;
    wt_body(W1 + (size_t)z * 512 * 64, W1Tb + (size_t)z * 64 * 512, 512, 64, 512, m0, Lw);
  } else if (b < PB_BM + PB_XC + PB_W1 + PB_WI) {
    int i = (b - (PB_BM + PB_XC + PB_W1)) * 256 + tid;
    if (i < 2048) cast8(wint1, wint1b, i);
  } else if (b < PB_BM + PB_XC + PB_W1 + PB_WI + PB_WF) {
    int i = (b - (PB_BM + PB_XC + PB_W1 + PB_WI)) * 256 + tid;
    if (i < 1024) cast8(wfus1, wfus1b, i);
  } else {
    int z = b - (PB_BM + PB_XC + PB_W1 + PB_WI + PB_WF);
    wt_body(W2 + (size_t)z * 64 * 32, W2Tb + (size_t)z * 32 * 64, 64, 32, 64, 0, Lw);
  }
}

// ---------------- bf16 MFMA GEMM, 32 rows x OW cols per 128-thr block ----------------
// AF=1: A-tile generated from stage-1 PV partials (normalize+ELU+bf16 on the fly).
// MODE=1: epilogue writes WhT in PRE-SWIZZLED tile layout: tile t = rows [64t,64t+64),
//   byte offset within tile = (o*128 + (m&63)*2) ^ ((o&7)<<4); tile stride = OW*128 B.
template <int OW, int KC, int MODE, int ACT, int AF>
__global__ __launch_bounds__(128)
void k_xw(const unsigned short* __restrict__ Ab, long long boffA,
          const unsigned short* __restrict__ Bb, long long boffB,
          const float* __restrict__ aux,
          unsigned short* __restrict__ Wo,
          long long boffW,
          float* __restrict__ f1o, float* __restrict__ f2o,
          const float* __restrict__ rs4,
          int colStrideZ, int ldC) {
  constexpr int NCT = OW / 16;
  const int z = blockIdx.z;
  const int n0 = blockIdx.x * 32;
  const int ocol0 = blockIdx.y * OW;
  const unsigned short* A = Ab + (AF ? 0 : boffA * z);
  const unsigned short* B = Bb + boffB * z;
  const int tid = threadIdx.x;
  const int l = tid & 63, g = l >> 4, li = l & 15;
  const int r0 = 16 * (tid >> 6);
  __shared__ __align__(16) unsigned short As[32 * 64];
  __shared__ __align__(16) unsigned short Bs[OW * 64];
  float4v acc[NCT];
#pragma unroll
  for (int ct = 0; ct < NCT; ++ct) acc[ct] = {0.f, 0.f, 0.f, 0.f};
  for (int k0 = 0; k0 < KC; k0 += 64) {
    for (int i = tid; i < 256; i += 128) {
      int r = i >> 3, c8 = i & 7;
      uint4 v = {0u, 0u, 0u, 0u};
      int n = n0 + r;
      if (n < NNODE) {
        if (AF) {
          // stage-1 PV partials: h = k0/64, zp = a*4+h; val = ELU((Σks p)·inv)
          int zp = z * 4 + (k0 >> 6);
          float s = rs4[(size_t)(0 * 8 + zp) * NNODE + n] +
                    rs4[(size_t)(1 * 8 + zp) * NNODE + n] +
                    rs4[(size_t)(2 * 8 + zp) * NNODE + n] +
                    rs4[(size_t)(3 * 8 + zp) * NNODE + n];
          float inv = (s > 0.f) ? 1.f / s : 0.f;
          size_t base = ((size_t)zp * NNODE + n) * 64 + 8 * c8;
          short8v p0 = *reinterpret_cast<const short8v*>(A + base);
          short8v p1 = *reinterpret_cast<const short8v*>(A + (size_t)8 * NNODE * 64 + base);
          short8v p2 = *reinterpret_cast<const short8v*>(A + (size_t)16 * NNODE * 64 + base);
          short8v p3 = *reinterpret_cast<const short8v*>(A + (size_t)24 * NNODE * 64 + base);
          short8v w;
#pragma unroll
          for (int e = 0; e < 8; ++e) {
            float sv = b2f((unsigned short)p0[e]) + b2f((unsigned short)p1[e]) +
                       b2f((unsigned short)p2[e]) + b2f((unsigned short)p3[e]);
            sv *= inv;
            sv = sv > 0.f ? sv : (__expf(sv) - 1.f);
            w[e] = f2b(sv);
          }
          v = *reinterpret_cast<uint4*>(&w);
        } else {
          v = *reinterpret_cast<const uint4*>(A + (size_t)n * KC + k0 + 8 * c8);
        }
      }
      int boff = (r * 128 + c8 * 16) ^ ((r & 7) << 4);
      *reinterpret_cast<uint4*>(reinterpret_cast<char*>(As) + boff) = v;
    }
    for (int i = tid; i < OW * 8; i += 128) {
      int ro = i >> 3, c8 = i & 7;
      uint4 v = *reinterpret_cast<const uint4*>(B + (size_t)(ocol0 + ro) * KC + k0 + 8 * c8);
      int boff = (ro * 128 + c8 * 16) ^ ((ro & 7) << 4);
      *reinterpret_cast<uint4*>(reinterpret_cast<char*>(Bs) + boff) = v;
    }
    __syncthreads();
#pragma unroll
    for (int q = 0; q < 2; ++q) {
      int aoff = ((r0 + li) * 128 + q * 64 + 16 * g) ^ ((li & 7) << 4);
      short8v afr = *reinterpret_cast<const short8v*>(
          reinterpret_cast<const char*>(As) + aoff);
#pragma unroll
      for (int ct = 0; ct < NCT; ++ct) {
        int orow = ct * 16 + li;
        int boff = (orow * 128 + q * 64 + 16 * g) ^ ((li & 7) << 4);
        short8v bfr = *reinterpret_cast<const short8v*>(
            reinterpret_cast<const char*>(Bs) + boff);
        acc[ct] = __builtin_amdgcn_mfma_f32_16x16x32_bf16(afr, bfr, acc[ct], 0, 0, 0);
      }
    }
    __syncthreads();
  }
  if (MODE == 1) {
    const float* av = aux + (size_t)z * 2 * OW;
    float p1[4] = {0.f, 0.f, 0.f, 0.f}, p2[4] = {0.f, 0.f, 0.f, 0.f};
#pragma unroll
    for (int ct = 0; ct < NCT; ++ct) {
      float a1v = av[ct * 16 + li];
      float a2v = av[OW + ct * 16 + li];
#pragma unroll
      for (int j = 0; j < 4; ++j) {
        p1[j] += acc[ct][j] * a1v;
        p2[j] += acc[ct][j] * a2v;
      }
    }
#pragma unroll
    for (int off = 1; off < 16; off <<= 1) {
#pragma unroll
      for (int j = 0; j < 4; ++j) {
        p1[j] += __shfl_xor(p1[j], off);
        p2[j] += __shfl_xor(p2[j], off);
      }
    }
    // pre-swizzled tile write (matches pvp's LDS image exactly)
    unsigned short* WT = Wo + boffW * z;
    const int m = n0 + r0 + 4 * g;
    const int tile = m >> 6, mloc = m & 63;
    char* tbase = reinterpret_cast<char*>(WT) + (size_t)tile * (OW * 128);
#pragma unroll
    for (int ct = 0; ct < NCT; ++ct) {
      int o = ocol0 + ct * 16 + li;
      short4v w;
#pragma unroll
      for (int j = 0; j < 4; ++j) w[j] = f2b(acc[ct][j]);
      int boff = (o * 128 + mloc * 2) ^ ((o & 7) << 4);
      *reinterpret_cast<short4v*>(tbase + boff) = w;
    }
    if (li == 0) {
#pragma unroll
      for (int j = 0; j < 4; ++j) {
        int n = n0 + r0 + 4 * g + j;
        if (n < NNODE) {
          f1o[(size_t)z * NNODE + n] = p1[j] * LOG2E;
          f2o[(size_t)z * NNODE + n] = p2[j] * LOG2E;
        }
      }
    }
  } else {
#pragma unroll
    for (int ct = 0; ct < NCT; ++ct) {
      float b = aux[ocol0 + ct * 16 + li];
#pragma unroll
      for (int j = 0; j < 4; ++j) {
        int n = n0 + r0 + 4 * g + j;
        if (n < NNODE) {
          float v = acc[ct][j] + b;
          if (ACT == 1) v = v > 0.f ? v : (__expf(v) - 1.f);
          Wo[(size_t)n * ldC + z * colStrideZ + ocol0 + ct * 16 + li] = (unsigned short)f2b(v);
        }
      }
    }
  }
}

// ---------------- MFMA PV, K-split partials: 64 rows, 256 thr, 4 waves ----------------
// WhT is pre-swizzled per 64-k tile -> staging is a LINEAR 16B copy.
template <int O, int CPS, bool PB16>
__global__ __launch_bounds__(256)
void k_pvp(const unsigned short* __restrict__ WhT,
           const float* __restrict__ f1, const float* __restrict__ f2,
           const unsigned long long* __restrict__ bm,
           void* __restrict__ Cpart, float* __restrict__ rsum) {
  constexpr int NCT = O / 16;
  const int z = blockIdx.z, a = z >> 2;
  const int ks = blockIdx.y;
  const int n0 = blockIdx.x * 64;
  const int kc0 = ks * CPS;
  const int nch = (NCHUNK - kc0 < CPS) ? (NCHUNK - kc0) : CPS;
  const int tid = threadIdx.x;
  const int l = tid & 63, li = l & 15, g = l >> 4;
  const int r0 = 16 * (tid >> 6);  // 0,16,32,48 (4 waves)
  const unsigned short* WT = WhT + (size_t)z * O * LDT;
  const float* f2B = f2 + (size_t)z * NNODE;
  const unsigned long long* bmA = bm + (size_t)a * NNODE * NCHUNK;
  __shared__ __align__(16) unsigned short Whs[2][O * 64];
  __shared__ __align__(16) float F2d[2][64];
  __shared__ unsigned long long Bw2[2][64];
  __shared__ float F1s[64];
  if (tid < 64) {
    int n = n0 + tid;
    F1s[tid] = (n < NNODE) ? f1[(size_t)z * NNODE + n] : 0.f;
  }
  short8v onesf;
  {
    short ov = (li == 0) ? (short)0x3F80 : (short)0;
#pragma unroll
    for (int e = 0; e < 8; ++e) onesf[e] = ov;
  }
  auto stage = [&](int t, int buf) {
    if (tid < 64) {
      int n = n0 + tid;
      Bw2[buf][tid] = (n < NNODE) ? bmA[(size_t)n * NCHUNK + kc0 + t] : 0ULL;
    } else if (tid < 128) {
      int m = (kc0 + t) * 64 + (tid - 64);
      F2d[buf][tid - 64] = (m < NNODE) ? f2B[m] : 0.f;
    }
    const uint4* tb = reinterpret_cast<const uint4*>(WT + (size_t)(kc0 + t) * (O * 64));
    uint4* lb = reinterpret_cast<uint4*>(Whs[buf]);
    for (int i = tid; i < O * 8; i += 256) lb[i] = tb[i];
  };
  float4v acc[NCT];
#pragma unroll
  for (int ct = 0; ct < NCT; ++ct) acc[ct] = {0.f, 0.f, 0.f, 0.f};
  float4v accs = {0.f, 0.f, 0.f, 0.f};
  stage(0, 0);
  __syncthreads();
  for (int t = 0; t < nch; ++t) {
    int buf = t & 1;
    if (t + 1 < nch) stage(t + 1, buf ^ 1);
    const unsigned long long bwr = Bw2[buf][r0 + li];
    const float f1v = F1s[r0 + li];
    short8v afr[2];
#pragma unroll
    for (int q = 0; q < 2; ++q) {
      int koff = 32 * q + 8 * g;
      unsigned bits = (unsigned)(bwr >> koff) & 0xffu;
      const float4 fa = *reinterpret_cast<const float4*>(&F2d[buf][koff]);
      const float4 fb = *reinterpret_cast<const float4*>(&F2d[buf][koff + 4]);
      float f2v[8] = {fa.x, fa.y, fa.z, fa.w, fb.x, fb.y, fb.z, fb.w};
#pragma unroll
      for (int e = 0; e < 8; ++e) {
        float tt = f1v + f2v[e];
        tt = fmaxf(tt, ALPHA * tt);
        tt = (bits & (1u << e)) ? tt : -1.0e30f;   // exp2(-1e30) = 0
        afr[q][e] = f2b(__builtin_amdgcn_exp2f(tt));
      }
    }
#pragma unroll
    for (int ct = 0; ct < NCT; ++ct) {
      int orow = ct * 16 + li;
#pragma unroll
      for (int q = 0; q < 2; ++q) {
        int boff = (orow * 128 + q * 64 + 16 * g) ^ ((li & 7) << 4);
        short8v bfr = *reinterpret_cast<const short8v*>(
            reinterpret_cast<const char*>(Whs[buf]) + boff);
        acc[ct] = __builtin_amdgcn_mfma_f32_16x16x32_bf16(afr[q], bfr, acc[ct], 0, 0, 0);
      }
    }
    accs = __builtin_amdgcn_mfma_f32_16x16x32_bf16(afr[0], onesf, accs, 0, 0, 0);
    accs = __builtin_amdgcn_mfma_f32_16x16x32_bf16(afr[1], onesf, accs, 0, 0, 0);
    __syncthreads();
  }
  if (PB16) {
    unsigned short* Cp = (unsigned short*)Cpart + ((size_t)ks * 8 + z) * NNODE * O;
#pragma unroll
    for (int j = 0; j < 4; ++j) {
      int n = n0 + r0 + 4 * g + j;
      if (n < NNODE) {
#pragma unroll
        for (int ct = 0; ct < NCT; ++ct)
          Cp[(size_t)n * O + ct * 16 + li] = (unsigned short)f2b(acc[ct][j]);
      }
    }
  } else {
    float* Cp = (float*)Cpart + ((size_t)ks * 8 + z) * NNODE * O;
#pragma unroll
    for (int j = 0; j < 4; ++j) {
      int n = n0 + r0 + 4 * g + j;
      if (n < NNODE) {
#pragma unroll
        for (int ct = 0; ct < NCT; ++ct)
          Cp[(size_t)n * O + ct * 16 + li] = acc[ct][j];
      }
    }
  }
  if (li == 0) {
#pragma unroll
    for (int j = 0; j < 4; ++j) {
      int n = n0 + r0 + 4 * g + j;
      if (n < NNODE) rsum[((size_t)ks * 8 + z) * NNODE + n] = accs[j];
    }
  }
}

// ---------------- fused tail: pvred2 + int2 + fus2 + log_softmax (+ L1) ----------
__global__ __launch_bounds__(256)
void k_tail(const float* __restrict__ Cpf, const float* __restrict__ rs4,
            const float* __restrict__ wint2, const float* __restrict__ bint2,
            const float* __restrict__ wfus2, const float* __restrict__ bfus2,
            const float* __restrict__ wfus1, float* __restrict__ out) {
  const int tid = threadIdx.x;
  if (blockIdx.x == 750) {
    __shared__ float red[256];
    float s1 = 0.f, s2 = 0.f;
    for (int i = tid; i < 64 * 128; i += 256) s1 += fabsf(wfus1[i]);
    if (tid < 128) s2 = fabsf(wfus2[tid]);
    red[tid] = s1 / 8192.f + s2 / 128.f;
    __syncthreads();
    for (int off = 128; off; off >>= 1) {
      if (tid < off) red[tid] += red[tid + off];
      __syncthreads();
    }
    if (tid == 0) out[24000] = red[0];
    return;
  }
  __shared__ float T2s[4][16];
  const int w = tid >> 6, l = tid & 63;
  const int n = blockIdx.x * 4 + w;
  const int o = l & 15, q = l >> 4;     // t2 output index, k-quarter (== head h)
  const int zz = o >> 3, c = o & 7;
  const int zp = zz * 4 + q;
  float s4 = rs4[(size_t)(0 * 8 + zp) * NNODE + n] +
             rs4[(size_t)(1 * 8 + zp) * NNODE + n] +
             rs4[(size_t)(2 * 8 + zp) * NNODE + n] +
             rs4[(size_t)(3 * 8 + zp) * NNODE + n];
  float inv = (s4 > 0.f) ? 1.f / s4 : 0.f;
  const float* wr = wint2 + (size_t)c * 128 + q * 32;
  size_t base = ((size_t)zp * NNODE + n) * 32;
  const size_t pls = (size_t)8 * NNODE * 32;  // ks-plane stride
  float s = 0.f;
#pragma unroll
  for (int i = 0; i < 8; ++i) {
    float4 p0 = *reinterpret_cast<const float4*>(Cpf + base + 4 * i);
    float4 p1 = *reinterpret_cast<const float4*>(Cpf + pls + base + 4 * i);
    float4 p2 = *reinterpret_cast<const float4*>(Cpf + 2 * pls + base + 4 * i);
    float4 p3 = *reinterpret_cast<const float4*>(Cpf + 3 * pls + base + 4 * i);
    float4 wv = *reinterpret_cast<const float4*>(wr + 4 * i);
    float v0 = (p0.x + p1.x + p2.x + p3.x) * inv;
    float v1 = (p0.y + p1.y + p2.y + p3.y) * inv;
    float v2 = (p0.z + p1.z + p2.z + p3.z) * inv;
    float v3 = (p0.w + p1.w + p2.w + p3.w) * inv;
    v0 = v0 > 0.f ? v0 : (__expf(v0) - 1.f);
    v1 = v1 > 0.f ? v1 : (__expf(v1) - 1.f);
    v2 = v2 > 0.f ? v2 : (__expf(v2) - 1.f);
    v3 = v3 > 0.f ? v3 : (__expf(v3) - 1.f);
    s = fmaf(v0, wv.x, s); s = fmaf(v1, wv.y, s);
    s = fmaf(v2, wv.z, s); s = fmaf(v3, wv.w, s);
  }
  s += __shfl_xor(s, 16);
  s += __shfl_xor(s, 32);
  if (q == 0) {
    float v = s + bint2[c];
    v = v > 0.f ? v : (__expf(v) - 1.f);
    T2s[w][o] = v;
  }
  if (l < 8) {
    float v = bfus2[l];
#pragma unroll
    for (int k = 0; k < 16; ++k) v = fmaf(T2s[w][k], wfus2[l * 16 + k], v);
    float mx = v;
    mx = fmaxf(mx, __shfl_xor(mx, 1, 8));
    mx = fmaxf(mx, __shfl_xor(mx, 2, 8));
    mx = fmaxf(mx, __shfl_xor(mx, 4, 8));
    float ex = __expf(v - mx);
    float sm = ex;
    sm += __shfl_xor(sm, 1, 8);
    sm += __shfl_xor(sm, 2, 8);
    sm += __shfl_xor(sm, 4, 8);
    float ls = __logf(sm) + mx;
    out[(size_t)n * 8 + l] = v - ls;
  }
}

extern "C" void kernel_launch(void* const* d_in, const int* in_sizes, int n_in,
                              void* d_out, int out_size, void* d_ws, size_t ws_size,
                              hipStream_t stream) {
  const float* x = (const float*)d_in[0];
  const int* adj = (const int*)d_in[1];
  const float* W1 = (const float*)d_in[2];
  const float* a1 = (const float*)d_in[3];
  const float* W2 = (const float*)d_in[4];
  const float* a2 = (const float*)d_in[5];
  const float* wint1 = (const float*)d_in[6];
  const float* bint1 = (const float*)d_in[7];
  const float* wfus1 = (const float*)d_in[8];
  const float* bfus1 = (const float*)d_in[9];
  const float* wint2 = (const float*)d_in[10];
  const float* bint2 = (const float*)d_in[11];
  const float* wfus2 = (const float*)d_in[12];
  const float* bfus2 = (const float*)d_in[13];
  float* out = (float*)d_out;

  // workspace layout (float offsets); peak 5,541,600 floats = 22.2 MB
  float* W = (float*)d_ws;
  unsigned long long* bm = (unsigned long long*)d_ws;          // [2][3000][47] = 0..564000
  unsigned short* xb = (unsigned short*)(W + 564000);          // [3000][512] bf16, dead after xw1
  unsigned short* W1Tb = (unsigned short*)(W + 1332000);       // [8][64][512] bf16
  unsigned short* wint1b = (unsigned short*)(W + 1463072);     // [64][256] bf16
  unsigned short* wfus1b = (unsigned short*)(W + 1471264);     // [64][128] bf16
  unsigned short* W2Tb = (unsigned short*)(W + 1475360);       // [8][32][64] bf16
  float* f1b = W + 1483552;                                    // [8][3000]
  float* f2g = W + 1507552;                                    // [8][3000]
  unsigned short* WhT1 = (unsigned short*)(W + 1531552);       // [8][47 tiles][64][64] bf16 swizzled
  unsigned short* t1b = (unsigned short*)(W + 1531552);        // [3000][128] bf16 (after int1)
  unsigned short* out1b = (unsigned short*)(W + 1723552);      // [3000][64] bf16
  unsigned short* WhT2 = (unsigned short*)(W + 1819552);       // [8][47 tiles][32][64] bf16 swizzled
  float* rsumw = W + 2373600;                                  // [4][8][3000]
  void* Cpart = (void*)(W + 2469600);                          // bf16 [4][8][3000][64] / f32 [4][8][3000][32]

  // fused preprocessing (bitmask + casts + weight transposes), one launch
  k_prep<<<dim3(PREP_BLOCKS), 256, 0, stream>>>(
      adj, (unsigned char*)bm, x, xb, W1, W1Tb, wint1, wint1b, wfus1, wfus1b, W2, W2Tb);

  // stage 1: Wh1 + f1/f2 (pre-scaled) + WhT1 (pre-swizzled), fused
  k_xw<64, 512, 1, 0, 0><<<dim3(94, 1, 8), 128, 0, stream>>>(
      xb, 0, W1Tb, 64 * 512, a1, WhT1, (long long)64 * LDT, f1b, f2g, nullptr, 0, 0);
  // PV stage 1 (K-split 4, bf16 partials)
  k_pvp<64, 12, true><<<dim3(47, 4, 8), 256, 0, stream>>>(WhT1, f1b, f2g, bm, Cpart, rsumw);
  // int1 (fused pvred1 in A-path) -> t1b bf16
  k_xw<32, 256, 0, 1, 1><<<dim3(94, 2, 2), 128, 0, stream>>>(
      (const unsigned short*)Cpart, 0, wint1b, 0, bint1, t1b, 0, nullptr, nullptr,
      rsumw, 64, 128);
  // fus1 -> out1b bf16
  k_xw<32, 128, 0, 0, 0><<<dim3(94, 2, 1), 128, 0, stream>>>(
      t1b, 0, wfus1b, 0, bfus1, out1b, 0, nullptr, nullptr, nullptr, 0, 64);

  // stage 2: Wh2 + f1/f2 (pre-scaled) + WhT2 (pre-swizzled), fused
  k_xw<32, 64, 1, 0, 0><<<dim3(94, 1, 8), 128, 0, stream>>>(
      out1b, 0, W2Tb, 32 * 64, a2, WhT2, (long long)32 * LDT, f1b, f2g, nullptr, 0, 0);
  // PV stage 2 (K-split 4, fp32 partials)
  k_pvp<32, 12, false><<<dim3(47, 4, 8), 256, 0, stream>>>(WhT2, f1b, f2g, bm, Cpart, rsumw);

  // fused tail: pvred2 + int2 + fus2 + log_softmax + L1
  k_tail<<<dim3(751), 256, 0, stream>>>(
      (const float*)Cpart, rsumw, wint2, bint2, wfus2, bfus2, wfus1, out);
}